// Round 5
// baseline (432.300 us; speedup 1.0000x reference)
//
#include <hip/hip_runtime.h>
#include <cstdint>
#include <cstddef>

typedef unsigned short u16;
typedef __attribute__((ext_vector_type(8))) short short8;
typedef __attribute__((ext_vector_type(4))) short sv4;    // 4 bf16 frag
typedef __attribute__((ext_vector_type(4))) float f32x4;
typedef __attribute__((ext_vector_type(2))) unsigned int u32x2;
typedef __attribute__((ext_vector_type(4))) unsigned int u32x4;

__device__ __forceinline__ u16 f2bf(float f) {
  unsigned int u = __builtin_bit_cast(unsigned int, f);
  u += 0x7FFFu + ((u >> 16) & 1u);
  return (u16)(u >> 16);
}
__device__ __forceinline__ float bf2f(u16 v) {
  return __builtin_bit_cast(float, ((unsigned int)v) << 16);
}

// packed f32x2 -> bf16x2 (RNE). gfx950 has v_cvt_pk_bf16_f32; guard builtin
// probe with __HIP_DEVICE_COMPILE__ (host pass reports no amdgcn builtins, r7).
__device__ __forceinline__ unsigned int pk_bf16(float a, float b) {
#if defined(__HIP_DEVICE_COMPILE__) && __has_builtin(__builtin_amdgcn_cvt_pk_bf16_f32)
  typedef __attribute__((ext_vector_type(2))) __bf16 bf16x2;
  bf16x2 r = __builtin_amdgcn_cvt_pk_bf16_f32(a, b);
  return __builtin_bit_cast(unsigned int, r);
#else
  return (unsigned int)f2bf(a) | ((unsigned int)f2bf(b) << 16);
#endif
}

// 16x16x16 bf16 MFMA (device-gated probe — r7 lesson).
__device__ __forceinline__ f32x4 mfma_16x16x16_bf16(sv4 a, sv4 b, f32x4 c) {
#if defined(__HIP_DEVICE_COMPILE__)
#if __has_builtin(__builtin_amdgcn_mfma_f32_16x16x16bf16_1k)
  return __builtin_amdgcn_mfma_f32_16x16x16bf16_1k(a, b, c, 0, 0, 0);
#elif __has_builtin(__builtin_amdgcn_mfma_f32_16x16x16_bf16)
  return __builtin_amdgcn_mfma_f32_16x16x16_bf16(a, b, c, 0, 0, 0);
#else
  asm volatile("v_mfma_f32_16x16x16_bf16 %0, %1, %2, %0\n\ts_nop 7\n\ts_nop 4"
               : "+v"(c) : "v"(a), "v"(b));
  return c;
#endif
#else
  (void)a; (void)b;
  return c;   // host stub, never executed
#endif
}

// async global->LDS, 16B per lane; LDS dest = wave-uniform base + lane*16
// (kept for the GEMMs, where B/A panels ARE reused well via streaming tiles)
#define GLD_LDS(g, l) __builtin_amdgcn_global_load_lds( \
    (const __attribute__((address_space(1))) void*)(g), \
    (__attribute__((address_space(3))) void*)(l), 16, 0, 0)

// (1/8) * log2(e): folded into Wq/bq at convert time so attn's exp2 needs no mul
#define QSCL 0.18033688011112042f

// ---------------------------------------------------------------------------
// dtype probe: flag 1 = fp32 inputs (established on this harness), 0 = bf16.
// ---------------------------------------------------------------------------
__global__ void detect_dtype(const u16* __restrict__ x, int* __restrict__ flag)
{
  const int lane = threadIdx.x;          // 64 threads
  int hit = 0;
#pragma unroll
  for (int j = 0; j < 4; ++j) {
    float v = bf2f(x[lane * 4 + j]);
    if (!(v > -1000.f && v < 1000.f)) hit = 1;
  }
  unsigned long long any = __ballot(hit != 0);
  if (lane == 0) *flag = (any != 0ull) ? 1 : 0;
}

// ---------------------------------------------------------------------------
// Convert weights+biases to bf16: Wc=[Wq|Wk|Wv|Wo], bc=[bq|bk|bv|bo].
// Wq and bq are pre-scaled by QSCL (softmax scale fold).
// ---------------------------------------------------------------------------
__global__ __launch_bounds__(256)
void convert_wb(const void* Wq, const void* Wk, const void* Wv, const void* Wo,
                const void* bq, const void* bk, const void* bv, const void* bo,
                u16* __restrict__ Wc, u16* __restrict__ bc, const int* __restrict__ flag)
{
  const int fp32 = *flag;
  const size_t base = ((size_t)blockIdx.x * 256 + threadIdx.x) * 8;
  const void* src; u16* dst; size_t local; int sel;
  if (base < (size_t)4 * 1048576) {
    sel = (int)(base >> 20);
    local = base & 1048575u;
    src = (sel == 0) ? Wq : (sel == 1) ? Wk : (sel == 2) ? Wv : Wo;
    dst = Wc + (size_t)sel * 1048576 + local;
  } else {
    const size_t rem = base - (size_t)4 * 1048576;   // 0..4095
    sel = (int)(rem >> 10);
    local = rem & 1023u;
    src = (sel == 0) ? bq : (sel == 1) ? bk : (sel == 2) ? bv : bo;
    dst = bc + (size_t)sel * 1024 + local;
  }
  const float scale = (sel == 0) ? QSCL : 1.0f;
  if (fp32) {
    const float* s = (const float*)src + local;
    u32x4 w;
#pragma unroll
    for (int j = 0; j < 4; ++j) w[j] = pk_bf16(s[2 * j] * scale, s[2 * j + 1] * scale);
    *(short8*)dst = __builtin_bit_cast(short8, w);
  } else {
    const u16* s = (const u16*)src + local;
    if (sel == 0) {
      u32x4 w;
#pragma unroll
      for (int j = 0; j < 4; ++j)
        w[j] = pk_bf16(bf2f(s[2 * j]) * scale, bf2f(s[2 * j + 1]) * scale);
      *(short8*)dst = __builtin_bit_cast(short8, w);
    } else {
      *(short8*)dst = *(const short8*)s;
    }
  }
}

// x convert: grid*256*8 elements from src element offset b*2097152; dst from 0.
__global__ __launch_bounds__(256)
void convert_x_off(const void* __restrict__ x, u16* __restrict__ dst,
                   const int* __restrict__ flag, int b)
{
  const int fp32 = *flag;
  const size_t base = ((size_t)blockIdx.x * 256 + threadIdx.x) * 8;
  const size_t src_e = (size_t)b * 2048 * 1024 + base;
  if (fp32) {
    const float* s = (const float*)x + src_e;
    u32x4 w;
#pragma unroll
    for (int j = 0; j < 4; ++j) w[j] = pk_bf16(s[2 * j], s[2 * j + 1]);
    *(short8*)(dst + base) = __builtin_bit_cast(short8, w);
  } else {
    *(short8*)(dst + base) = *(const short8*)((const u16*)x + src_e);
  }
}

// ---------------------------------------------------------------------------
// GEMM (bf16 in/out): C[m,n] = sum_k A[m,k]*B[n,k] + bias[sel*1024 + n%1024].
// 128x128 tile, BK=32, 4 waves each 64x64 (m97 structure).
// r9: blockIdx.x = m-tile (fast) so concurrent blocks share one B panel in L2.
// ---------------------------------------------------------------------------
__global__ __launch_bounds__(256)
void gemm_bt(const u16* __restrict__ A,
             const u16* __restrict__ B0, const u16* __restrict__ B1, const u16* __restrict__ B2,
             const u16* __restrict__ bias, u16* __restrict__ C, int Ntot, int K)
{
  __shared__ __align__(16) u16 Alds[128 * 32];
  __shared__ __align__(16) u16 Blds[128 * 32];
  const int tid  = threadIdx.x;
  const int wave = tid >> 6, lane = tid & 63;
  const int quad = lane >> 4, l15 = lane & 15;
  const int m0  = blockIdx.x * 128;        // m fast-varying (L2 B-panel reuse)
  const int n0g = blockIdx.y * 128;
  const int sel = n0g >> 10;
  const u16* Bm = (sel == 0) ? B0 : ((sel == 1) ? B1 : B2);
  const u16* bb = bias + (size_t)sel * 1024;
  const int n0 = n0g & 1023;
  const int wr = (wave >> 1) * 64, wc = (wave & 1) * 64;

  f32x4 acc[4][4] = {};
  const int srow = lane >> 2;        // 0..15
  const int skc  = (lane & 3) * 8;   // 16B k-chunk
  const u16* Ag = A  + (size_t)(m0 + srow) * K + skc;
  const u16* Bg = Bm + (size_t)(n0 + srow) * K + skc;

  for (int kt = 0; kt < K; kt += 32) {
    __syncthreads();
#pragma unroll
    for (int t = 0; t < 2; ++t) {
      const int seg = wave * 2 + t;
      GLD_LDS(Ag + (size_t)(seg * 16) * K + kt, Alds + seg * 512);
      GLD_LDS(Bg + (size_t)(seg * 16) * K + kt, Blds + seg * 512);
    }
    __syncthreads();

    short8 af[4], bfr[4];
#pragma unroll
    for (int i = 0; i < 4; ++i)
      af[i] = *(const short8*)&Alds[(wr + i * 16 + l15) * 32 + quad * 8];
#pragma unroll
    for (int j = 0; j < 4; ++j)
      bfr[j] = *(const short8*)&Blds[(wc + j * 16 + l15) * 32 + quad * 8];
#pragma unroll
    for (int i = 0; i < 4; ++i)
#pragma unroll
      for (int j = 0; j < 4; ++j)
        acc[i][j] = __builtin_amdgcn_mfma_f32_16x16x32_bf16(af[i], bfr[j], acc[i][j], 0, 0, 0);
  }

#pragma unroll
  for (int i = 0; i < 4; ++i) {
    const int mr = m0 + wr + i * 16 + quad * 4;
#pragma unroll
    for (int j = 0; j < 4; ++j) {
      const int ncl = wc + j * 16 + l15;
      const float bvv = bf2f(bb[n0 + ncl]);
#pragma unroll
      for (int r = 0; r < 4; ++r)
        C[(size_t)(mr + r) * Ntot + n0g + ncl] = f2bf(acc[i][j][r] + bvv);
    }
  }
}

// ---------------------------------------------------------------------------
// Out-proj GEMM: writes d_out in dtype chosen by *flag. m-tile fast (r9).
// ---------------------------------------------------------------------------
__global__ __launch_bounds__(256)
void gemm_bt_out(const u16* __restrict__ A, const u16* __restrict__ Bm,
                 const u16* __restrict__ bias, void* __restrict__ C16,
                 void* __restrict__ C32, int Ntot, int K, const int* __restrict__ flag)
{
  __shared__ __align__(16) u16 Alds[128 * 32];
  __shared__ __align__(16) u16 Blds[128 * 32];
  const int tid  = threadIdx.x;
  const int wave = tid >> 6, lane = tid & 63;
  const int quad = lane >> 4, l15 = lane & 15;
  const int m0 = blockIdx.x * 128;
  const int n0 = blockIdx.y * 128;
  const int wr = (wave >> 1) * 64, wc = (wave & 1) * 64;

  f32x4 acc[4][4] = {};
  const int srow = lane >> 2;
  const int skc  = (lane & 3) * 8;
  const u16* Ag = A  + (size_t)(m0 + srow) * K + skc;
  const u16* Bg = Bm + (size_t)(n0 + srow) * K + skc;

  for (int kt = 0; kt < K; kt += 32) {
    __syncthreads();
#pragma unroll
    for (int t = 0; t < 2; ++t) {
      const int seg = wave * 2 + t;
      GLD_LDS(Ag + (size_t)(seg * 16) * K + kt, Alds + seg * 512);
      GLD_LDS(Bg + (size_t)(seg * 16) * K + kt, Blds + seg * 512);
    }
    __syncthreads();

    short8 af[4], bfr[4];
#pragma unroll
    for (int i = 0; i < 4; ++i)
      af[i] = *(const short8*)&Alds[(wr + i * 16 + l15) * 32 + quad * 8];
#pragma unroll
    for (int j = 0; j < 4; ++j)
      bfr[j] = *(const short8*)&Blds[(wc + j * 16 + l15) * 32 + quad * 8];
#pragma unroll
    for (int i = 0; i < 4; ++i)
#pragma unroll
      for (int j = 0; j < 4; ++j)
        acc[i][j] = __builtin_amdgcn_mfma_f32_16x16x32_bf16(af[i], bfr[j], acc[i][j], 0, 0, 0);
  }

  if (*flag != 0) {
    float* Cf = (float*)C32;
#pragma unroll
    for (int i = 0; i < 4; ++i) {
      const int mr = m0 + wr + i * 16 + quad * 4;
#pragma unroll
      for (int j = 0; j < 4; ++j) {
        const int ncl = wc + j * 16 + l15;
        const float bvv = bf2f(bias[n0 + ncl]);
#pragma unroll
        for (int r = 0; r < 4; ++r)
          Cf[(size_t)(mr + r) * Ntot + n0 + ncl] = acc[i][j][r] + bvv;
      }
    }
  } else {
    u16* Cb = (u16*)C16;
#pragma unroll
    for (int i = 0; i < 4; ++i) {
      const int mr = m0 + wr + i * 16 + quad * 4;
#pragma unroll
      for (int j = 0; j < 4; ++j) {
        const int ncl = wc + j * 16 + l15;
        const float bvv = bf2f(bias[n0 + ncl]);
#pragma unroll
        for (int r = 0; r < 4; ++r)
          Cb[(size_t)(mr + r) * Ntot + n0 + ncl] = f2bf(acc[i][j][r] + bvv);
      }
    }
  }
}

// ---------------------------------------------------------------------------
// Flash attention, S^T formulation (register-resident P). Q pre-scaled by
// QSCL at the projection, so exp2 applies directly to sacc.
//
// r4 post-mortem: even with panel colocation + lockstep (2 blocks/CU), L2
// absorbed only ~25% of logical K/V traffic. Cross-round evidence: r0 staged
// via plain loads -> 74% absorption; r2-r4 via global_load_lds -> 0-43%.
// Theory: lds-direct loads fill LDS without leaving reusable L2 lines
// (streaming allocation). r5: transport back to reg-staging (T14 split:
// load issued one full tile early; ds_write waits covered by ATILE), with
// LINEAR per-thread LDS dest (tid*16B -> zero write conflicts, unlike r0's
// row-major writes) and the SAME source-permuted K-swizzle / V-subtile
// layouts, so the conflict-free K reads + tr_read PV are untouched.
// ---------------------------------------------------------------------------

// issue next tile's loads into named regs (T14 issue-early half)
#define KLOAD() do {                               \
    kr = *(const short8*)kg0;                      \
    vr = *(const short8*)vg0;                      \
    kg0 += ADV; vg0 += ADV;                        \
  } while (0)

// write staged regs to LDS, linear dest (T14 write-late half; vmcnt wait
// inserted by compiler, covered by the ATILE between KLOAD and KWRITE)
#define KWRITE(KL, VL) do {                        \
    *(short8*)((KL) + ldst) = kr;                  \
    *(short8*)((VL) + ldst) = vr;                  \
  } while (0)

// compute one 64-kv tile from (KL, VL)
#define ATILE(KL, VL) do {                                                     \
    f32x4 sacc[4][2] = {};                                                     \
    _Pragma("unroll")                                                          \
    for (int kh = 0; kh < 2; ++kh) {                                           \
      const int kof = kh ? koff1 : koff0;                                      \
      short8 kf[4];                                                            \
      _Pragma("unroll")                                                        \
      for (int ct = 0; ct < 4; ++ct)                                           \
        kf[ct] = *(const short8*)&(KL)[ct * 1024 + kof];                       \
      __builtin_amdgcn_s_setprio(1);                                           \
      _Pragma("unroll")                                                        \
      for (int ct = 0; ct < 4; ++ct)                                           \
        _Pragma("unroll")                                                      \
        for (int rt = 0; rt < 2; ++rt)                                         \
          sacc[ct][rt] = __builtin_amdgcn_mfma_f32_16x16x32_bf16(              \
              kf[ct], qf[rt][kh], sacc[ct][rt], 0, 0, 0);                      \
      __builtin_amdgcn_s_setprio(0);                                           \
    }                                                                          \
    sv4 p16[4][2];                                                             \
    _Pragma("unroll")                                                          \
    for (int rt = 0; rt < 2; ++rt) {                                           \
      float rs = 0.f;                                                          \
      _Pragma("unroll")                                                        \
      for (int ct = 0; ct < 4; ++ct) {                                         \
        float p0 = __builtin_amdgcn_exp2f(sacc[ct][rt][0]);                    \
        float p1 = __builtin_amdgcn_exp2f(sacc[ct][rt][1]);                    \
        float p2 = __builtin_amdgcn_exp2f(sacc[ct][rt][2]);                    \
        float p3 = __builtin_amdgcn_exp2f(sacc[ct][rt][3]);                    \
        rs += (p0 + p1) + (p2 + p3);                                           \
        u32x2 pw;                                                              \
        pw[0] = pk_bf16(p0, p1);                                               \
        pw[1] = pk_bf16(p2, p3);                                               \
        p16[ct][rt] = __builtin_bit_cast(sv4, pw);                             \
      }                                                                        \
      rs += __shfl_xor(rs, 16, 64);                                            \
      rs += __shfl_xor(rs, 32, 64);                                            \
      lrow[rt] += rs;                                                          \
    }                                                                          \
    const __attribute__((address_space(3))) u16* vpb =                         \
        (const __attribute__((address_space(3))) u16*)(VL) + lane * 4;         \
    _Pragma("unroll")                                                          \
    for (int ct = 0; ct < 4; ++ct) {                                           \
      sv4 vfr[4];                                                              \
      _Pragma("unroll")                                                        \
      for (int dt = 0; dt < 4; ++dt)                                           \
        asm volatile("ds_read_b64_tr_b16 %0, %1"                               \
                     : "=v"(vfr[dt]) : "v"(vpb + ct * 1024 + dt * 256));       \
      asm volatile("s_waitcnt lgkmcnt(0)" ::: "memory");                       \
      __builtin_amdgcn_sched_barrier(0);  /* rule #18 */                       \
      __builtin_amdgcn_s_setprio(1);                                           \
      _Pragma("unroll")                                                        \
      for (int dt = 0; dt < 4; ++dt)                                           \
        _Pragma("unroll")                                                      \
        for (int rt = 0; rt < 2; ++rt)                                         \
          oaccT[dt][rt] = mfma_16x16x16_bf16(vfr[dt], p16[ct][rt],             \
                                             oaccT[dt][rt]);                   \
      __builtin_amdgcn_s_setprio(0);                                           \
    }                                                                          \
  } while (0)

// 1-D grid of 8*16*nz blocks, 512 threads (8 waves; wave w owns q-rows
// q0+w*32..+31). Panel-colocating decode: all 8 qt of a panel -> same XCD.
__global__ __launch_bounds__(512, 4)
void attn_s(const u16* __restrict__ QKV, u16* __restrict__ O)
{
  __shared__ __align__(16) u16 Ka[64 * 64], Kb[64 * 64];   // 8KB each
  __shared__ __align__(16) u16 Va[64 * 64], Vb[64 * 64];
  const int tid  = threadIdx.x;
  const int wave = tid >> 6, lane = tid & 63;
  const int quad = lane >> 4, l15 = lane & 15;

  // XCD-panel swizzle: all 8 qt of a panel -> same XCD, consecutive slots.
  const int i   = blockIdx.x;
  const int j   = i >> 3;
  const int qt  = j & 7;
  const int g   = (i & 7) + ((j >> 3) << 3);     // panel id = h + 16*z
  const int h   = g & 15;
  const int z   = g >> 4;

  const u16* QKVb = QKV + (size_t)z * 2048 * 3072;
  u16* Ob = O + (size_t)z * 2048 * 1024;
  const int q0 = qt * 256;

  // Q fragments (B-operand of x32: n=l15 -> q, k=quad*8+j -> d)
  short8 qf[2][2];
  const u16* Qb = QKVb + (size_t)(q0 + wave * 32) * 3072 + h * 64;
#pragma unroll
  for (int rt = 0; rt < 2; ++rt)
#pragma unroll
    for (int kh = 0; kh < 2; ++kh)
      qf[rt][kh] = *(const short8*)(Qb + (size_t)(rt * 16 + l15) * 3072 + kh * 32 + quad * 8);

  f32x4 oaccT[4][2] = {};    // [dt][rt]: C[m=d_local][n=q]
  float lrow[2] = {};

  // K frag u16 offsets (XOR swizzle; ct-independent since (ct*16+l15)&7==l15&7)
  const int koff0 = l15 * 64 + ((quad       ^ (l15 & 7)) << 3);
  const int koff1 = l15 * 64 + (((4 + quad) ^ (l15 & 7)) << 3);

  // Staging sources. 16B chunk id t = tid (512 chunks each for K and V);
  // LDS dest LINEAR = t*8 u16.
  //  K: t = kv*8 + c_lds; global chunk = c_lds ^ (kv&7)   (XOR involution)
  //  V: t = ct*128 + dt*32 + kvl*2 + half -> [ct][dt][kvl][16] subtile
  const u16* Kg = QKVb + 1024 + h * 64;
  const u16* Vg = QKVb + 2048 + h * 64;
  const int t0 = tid;
  const u16* kg0 = Kg + (size_t)(t0 >> 3) * 3072 + (((t0 & 7) ^ ((t0 >> 3) & 7)) << 3);
  const u16* vg0 = Vg + (size_t)((t0 >> 7) * 16 + ((t0 >> 1) & 15)) * 3072
                      + ((t0 >> 5) & 3) * 16 + ((t0 & 1) << 3);
  const int ldst = tid * 8;               // per-thread u16 dest (linear)
  const size_t ADV = (size_t)64 * 3072;   // one kv-tile of source rows
  short8 kr, vr;                          // staged regs (named; rule #20)

  KLOAD();                                // tile 0 loads
  KWRITE(Ka, Va);                         // tile 0 -> LDS (vmcnt wait here)
  KLOAD();                                // tile 1 loads in flight
#pragma unroll 1
  for (int it = 0; it < 16; ++it) {
    __syncthreads();                      // buf A writes visible
    ATILE(Ka, Va);                        // tile 2it  (covers tile-2it+1 loads)
    KWRITE(Kb, Vb);                       // tile 2it+1 -> LDS
    if (it != 15) KLOAD();                // tile 2it+2 loads
    __syncthreads();                      // buf B writes visible
    ATILE(Kb, Vb);                        // tile 2it+1 (covers tile-2it+2 loads)
    if (it != 15) {
      KWRITE(Ka, Va);                     // tile 2it+2 -> LDS
      KLOAD();                            // tile 2it+3 loads
    }
  }

  // store O[q][d]: q = q0+wave*32+rt*16+l15 (col), d = dt*16+quad*4+r (row)
#pragma unroll
  for (int rt = 0; rt < 2; ++rt) {
    const float inv = 1.f / lrow[rt];
    u16* Op = Ob + (size_t)(q0 + wave * 32 + rt * 16 + l15) * 1024 + h * 64;
#pragma unroll
    for (int dt = 0; dt < 4; ++dt) {
      u32x2 ow;
      ow[0] = pk_bf16(oaccT[dt][rt][0] * inv, oaccT[dt][rt][1] * inv);
      ow[1] = pk_bf16(oaccT[dt][rt][2] * inv, oaccT[dt][rt][3] * inv);
      *(sv4*)(Op + dt * 16 + quad * 4) = __builtin_bit_cast(sv4, ow);
    }
  }
}

// ---------------------------------------------------------------------------
extern "C" void kernel_launch(void* const* d_in, const int* in_sizes, int n_in,
                              void* d_out, int out_size, void* d_ws, size_t ws_size,
                              hipStream_t stream)
{
  // Common: flag + converted weights.
  int* flag = (int*)d_ws;
  u16* Wc   = (u16*)((char*)d_ws + 256);
  u16* bc   = Wc + (size_t)4 * 1048576;           // 4M u16
  char* after_wb = (char*)(bc + 4096);

  detect_dtype<<<1, 64, 0, stream>>>((const u16*)d_in[0], flag);
  convert_wb<<<2050, 256, 0, stream>>>(d_in[1], d_in[3], d_in[5], d_in[7],
                                       d_in[2], d_in[4], d_in[6], d_in[8],
                                       Wc, bc, flag);

  const size_t need_batched =
      (size_t)(after_wb - (char*)d_ws) + ((size_t)8192 * 3072 + (size_t)8192 * 1024) * 2;

  if (ws_size >= need_batched) {
    // ---- batched path: one launch per stage, full-device grids ----
    u16* QKV = (u16*)after_wb;
    u16* xO  = QKV + (size_t)8192 * 3072;   // xc before QKV-GEMM; O after attn

    convert_x_off<<<4096, 256, 0, stream>>>(d_in[0], xO, flag, 0);
    gemm_bt<<<dim3(64, 24), 256, 0, stream>>>(xO, Wc, Wc + 1048576, Wc + 2097152,
                                              bc, QKV, 3072, 1024);
    attn_s<<<512, 512, 0, stream>>>(QKV, xO);
    gemm_bt_out<<<dim3(64, 8), 256, 0, stream>>>(xO, Wc + (size_t)3 * 1048576,
                                                 bc + 3 * 1024, d_out, d_out,
                                                 1024, 1024, flag);
  } else {
    // ---- fallback: per-batch path (ws ~29.4 MB, proven) ----
    u16* xc   = (u16*)after_wb;
    u16* QKVb = xc + (size_t)2048 * 1024;
    u16* Obb  = QKVb + (size_t)2048 * 3072;
    for (int b = 0; b < 4; ++b) {
      convert_x_off<<<1024, 256, 0, stream>>>(d_in[0], xc, flag, b);
      gemm_bt<<<dim3(16, 24), 256, 0, stream>>>(xc, Wc, Wc + 1048576, Wc + 2097152,
                                                bc, QKVb, 3072, 1024);
      attn_s<<<128, 512, 0, stream>>>(QKVb, Obb);
      void* outb16 = (void*)((char*)d_out + (size_t)b * 2048 * 1024 * 2);
      void* outb32 = (void*)((char*)d_out + (size_t)b * 2048 * 1024 * 4);
      gemm_bt_out<<<dim3(16, 8), 256, 0, stream>>>(Obb, Wc + (size_t)3 * 1048576,
                                                   bc + 3 * 1024, outb16, outb32,
                                                   1024, 1024, flag);
    }
  }
}

// Round 6
// 308.492 us; speedup vs baseline: 1.4013x; 1.4013x over previous
//
#include <hip/hip_runtime.h>
#include <cstdint>
#include <cstddef>

typedef unsigned short u16;
typedef __attribute__((ext_vector_type(8))) short short8;
typedef __attribute__((ext_vector_type(4))) short sv4;    // 4 bf16 frag
typedef __attribute__((ext_vector_type(4))) float f32x4;
typedef __attribute__((ext_vector_type(2))) unsigned int u32x2;
typedef __attribute__((ext_vector_type(4))) unsigned int u32x4;

__device__ __forceinline__ u16 f2bf(float f) {
  unsigned int u = __builtin_bit_cast(unsigned int, f);
  u += 0x7FFFu + ((u >> 16) & 1u);
  return (u16)(u >> 16);
}
__device__ __forceinline__ float bf2f(u16 v) {
  return __builtin_bit_cast(float, ((unsigned int)v) << 16);
}

// packed f32x2 -> bf16x2 (RNE). gfx950 has v_cvt_pk_bf16_f32; guard builtin
// probe with __HIP_DEVICE_COMPILE__ (host pass reports no amdgcn builtins, r7).
__device__ __forceinline__ unsigned int pk_bf16(float a, float b) {
#if defined(__HIP_DEVICE_COMPILE__) && __has_builtin(__builtin_amdgcn_cvt_pk_bf16_f32)
  typedef __attribute__((ext_vector_type(2))) __bf16 bf16x2;
  bf16x2 r = __builtin_amdgcn_cvt_pk_bf16_f32(a, b);
  return __builtin_bit_cast(unsigned int, r);
#else
  return (unsigned int)f2bf(a) | ((unsigned int)f2bf(b) << 16);
#endif
}

// 16x16x16 bf16 MFMA (device-gated probe — r7 lesson).
__device__ __forceinline__ f32x4 mfma_16x16x16_bf16(sv4 a, sv4 b, f32x4 c) {
#if defined(__HIP_DEVICE_COMPILE__)
#if __has_builtin(__builtin_amdgcn_mfma_f32_16x16x16bf16_1k)
  return __builtin_amdgcn_mfma_f32_16x16x16bf16_1k(a, b, c, 0, 0, 0);
#elif __has_builtin(__builtin_amdgcn_mfma_f32_16x16x16_bf16)
  return __builtin_amdgcn_mfma_f32_16x16x16_bf16(a, b, c, 0, 0, 0);
#else
  asm volatile("v_mfma_f32_16x16x16_bf16 %0, %1, %2, %0\n\ts_nop 7\n\ts_nop 4"
               : "+v"(c) : "v"(a), "v"(b));
  return c;
#endif
#else
  (void)a; (void)b;
  return c;   // host stub, never executed
#endif
}

// async global->LDS, 16B per lane; LDS dest = wave-uniform base + lane*16
// (used by the GEMMs, where it is proven fast on this harness)
#define GLD_LDS(g, l) __builtin_amdgcn_global_load_lds( \
    (const __attribute__((address_space(1))) void*)(g), \
    (__attribute__((address_space(3))) void*)(l), 16, 0, 0)

// (1/8) * log2(e): folded into Wq/bq at convert time so attn's exp2 needs no mul
#define QSCL 0.18033688011112042f

// ---------------------------------------------------------------------------
// dtype probe: flag 1 = fp32 inputs (established on this harness), 0 = bf16.
// ---------------------------------------------------------------------------
__global__ void detect_dtype(const u16* __restrict__ x, int* __restrict__ flag)
{
  const int lane = threadIdx.x;          // 64 threads
  int hit = 0;
#pragma unroll
  for (int j = 0; j < 4; ++j) {
    float v = bf2f(x[lane * 4 + j]);
    if (!(v > -1000.f && v < 1000.f)) hit = 1;
  }
  unsigned long long any = __ballot(hit != 0);
  if (lane == 0) *flag = (any != 0ull) ? 1 : 0;
}

// ---------------------------------------------------------------------------
// Convert weights+biases to bf16: Wc=[Wq|Wk|Wv|Wo], bc=[bq|bk|bv|bo].
// Wq and bq are pre-scaled by QSCL (softmax scale fold).
// ---------------------------------------------------------------------------
__global__ __launch_bounds__(256)
void convert_wb(const void* Wq, const void* Wk, const void* Wv, const void* Wo,
                const void* bq, const void* bk, const void* bv, const void* bo,
                u16* __restrict__ Wc, u16* __restrict__ bc, const int* __restrict__ flag)
{
  const int fp32 = *flag;
  const size_t base = ((size_t)blockIdx.x * 256 + threadIdx.x) * 8;
  const void* src; u16* dst; size_t local; int sel;
  if (base < (size_t)4 * 1048576) {
    sel = (int)(base >> 20);
    local = base & 1048575u;
    src = (sel == 0) ? Wq : (sel == 1) ? Wk : (sel == 2) ? Wv : Wo;
    dst = Wc + (size_t)sel * 1048576 + local;
  } else {
    const size_t rem = base - (size_t)4 * 1048576;   // 0..4095
    sel = (int)(rem >> 10);
    local = rem & 1023u;
    src = (sel == 0) ? bq : (sel == 1) ? bk : (sel == 2) ? bv : bo;
    dst = bc + (size_t)sel * 1024 + local;
  }
  const float scale = (sel == 0) ? QSCL : 1.0f;
  if (fp32) {
    const float* s = (const float*)src + local;
    u32x4 w;
#pragma unroll
    for (int j = 0; j < 4; ++j) w[j] = pk_bf16(s[2 * j] * scale, s[2 * j + 1] * scale);
    *(short8*)dst = __builtin_bit_cast(short8, w);
  } else {
    const u16* s = (const u16*)src + local;
    if (sel == 0) {
      u32x4 w;
#pragma unroll
      for (int j = 0; j < 4; ++j)
        w[j] = pk_bf16(bf2f(s[2 * j]) * scale, bf2f(s[2 * j + 1]) * scale);
      *(short8*)dst = __builtin_bit_cast(short8, w);
    } else {
      *(short8*)dst = *(const short8*)s;
    }
  }
}

// x convert: grid*256*8 elements from src element offset b*2097152; dst from 0.
__global__ __launch_bounds__(256)
void convert_x_off(const void* __restrict__ x, u16* __restrict__ dst,
                   const int* __restrict__ flag, int b)
{
  const int fp32 = *flag;
  const size_t base = ((size_t)blockIdx.x * 256 + threadIdx.x) * 8;
  const size_t src_e = (size_t)b * 2048 * 1024 + base;
  if (fp32) {
    const float* s = (const float*)x + src_e;
    u32x4 w;
#pragma unroll
    for (int j = 0; j < 4; ++j) w[j] = pk_bf16(s[2 * j], s[2 * j + 1]);
    *(short8*)(dst + base) = __builtin_bit_cast(short8, w);
  } else {
    *(short8*)(dst + base) = *(const short8*)((const u16*)x + src_e);
  }
}

// ---------------------------------------------------------------------------
// GEMM (bf16 in/out): C[m,n] = sum_k A[m,k]*B[n,k] + bias[sel*1024 + n%1024].
// 128x128 tile, BK=32, 4 waves each 64x64 (m97 structure).
// r9: blockIdx.x = m-tile (fast) so concurrent blocks share one B panel in L2.
// ---------------------------------------------------------------------------
__global__ __launch_bounds__(256)
void gemm_bt(const u16* __restrict__ A,
             const u16* __restrict__ B0, const u16* __restrict__ B1, const u16* __restrict__ B2,
             const u16* __restrict__ bias, u16* __restrict__ C, int Ntot, int K)
{
  __shared__ __align__(16) u16 Alds[128 * 32];
  __shared__ __align__(16) u16 Blds[128 * 32];
  const int tid  = threadIdx.x;
  const int wave = tid >> 6, lane = tid & 63;
  const int quad = lane >> 4, l15 = lane & 15;
  const int m0  = blockIdx.x * 128;        // m fast-varying (L2 B-panel reuse)
  const int n0g = blockIdx.y * 128;
  const int sel = n0g >> 10;
  const u16* Bm = (sel == 0) ? B0 : ((sel == 1) ? B1 : B2);
  const u16* bb = bias + (size_t)sel * 1024;
  const int n0 = n0g & 1023;
  const int wr = (wave >> 1) * 64, wc = (wave & 1) * 64;

  f32x4 acc[4][4] = {};
  const int srow = lane >> 2;        // 0..15
  const int skc  = (lane & 3) * 8;   // 16B k-chunk
  const u16* Ag = A  + (size_t)(m0 + srow) * K + skc;
  const u16* Bg = Bm + (size_t)(n0 + srow) * K + skc;

  for (int kt = 0; kt < K; kt += 32) {
    __syncthreads();
#pragma unroll
    for (int t = 0; t < 2; ++t) {
      const int seg = wave * 2 + t;
      GLD_LDS(Ag + (size_t)(seg * 16) * K + kt, Alds + seg * 512);
      GLD_LDS(Bg + (size_t)(seg * 16) * K + kt, Blds + seg * 512);
    }
    __syncthreads();

    short8 af[4], bfr[4];
#pragma unroll
    for (int i = 0; i < 4; ++i)
      af[i] = *(const short8*)&Alds[(wr + i * 16 + l15) * 32 + quad * 8];
#pragma unroll
    for (int j = 0; j < 4; ++j)
      bfr[j] = *(const short8*)&Blds[(wc + j * 16 + l15) * 32 + quad * 8];
#pragma unroll
    for (int i = 0; i < 4; ++i)
#pragma unroll
      for (int j = 0; j < 4; ++j)
        acc[i][j] = __builtin_amdgcn_mfma_f32_16x16x32_bf16(af[i], bfr[j], acc[i][j], 0, 0, 0);
  }

#pragma unroll
  for (int i = 0; i < 4; ++i) {
    const int mr = m0 + wr + i * 16 + quad * 4;
#pragma unroll
    for (int j = 0; j < 4; ++j) {
      const int ncl = wc + j * 16 + l15;
      const float bvv = bf2f(bb[n0 + ncl]);
#pragma unroll
      for (int r = 0; r < 4; ++r)
        C[(size_t)(mr + r) * Ntot + n0g + ncl] = f2bf(acc[i][j][r] + bvv);
    }
  }
}

// ---------------------------------------------------------------------------
// Out-proj GEMM: writes d_out in dtype chosen by *flag. m-tile fast (r9).
// ---------------------------------------------------------------------------
__global__ __launch_bounds__(256)
void gemm_bt_out(const u16* __restrict__ A, const u16* __restrict__ Bm,
                 const u16* __restrict__ bias, void* __restrict__ C16,
                 void* __restrict__ C32, int Ntot, int K, const int* __restrict__ flag)
{
  __shared__ __align__(16) u16 Alds[128 * 32];
  __shared__ __align__(16) u16 Blds[128 * 32];
  const int tid  = threadIdx.x;
  const int wave = tid >> 6, lane = tid & 63;
  const int quad = lane >> 4, l15 = lane & 15;
  const int m0 = blockIdx.x * 128;
  const int n0 = blockIdx.y * 128;
  const int wr = (wave >> 1) * 64, wc = (wave & 1) * 64;

  f32x4 acc[4][4] = {};
  const int srow = lane >> 2;
  const int skc  = (lane & 3) * 8;
  const u16* Ag = A  + (size_t)(m0 + srow) * K + skc;
  const u16* Bg = Bm + (size_t)(n0 + srow) * K + skc;

  for (int kt = 0; kt < K; kt += 32) {
    __syncthreads();
#pragma unroll
    for (int t = 0; t < 2; ++t) {
      const int seg = wave * 2 + t;
      GLD_LDS(Ag + (size_t)(seg * 16) * K + kt, Alds + seg * 512);
      GLD_LDS(Bg + (size_t)(seg * 16) * K + kt, Blds + seg * 512);
    }
    __syncthreads();

    short8 af[4], bfr[4];
#pragma unroll
    for (int i = 0; i < 4; ++i)
      af[i] = *(const short8*)&Alds[(wr + i * 16 + l15) * 32 + quad * 8];
#pragma unroll
    for (int j = 0; j < 4; ++j)
      bfr[j] = *(const short8*)&Blds[(wc + j * 16 + l15) * 32 + quad * 8];
#pragma unroll
    for (int i = 0; i < 4; ++i)
#pragma unroll
      for (int j = 0; j < 4; ++j)
        acc[i][j] = __builtin_amdgcn_mfma_f32_16x16x32_bf16(af[i], bfr[j], acc[i][j], 0, 0, 0);
  }

  if (*flag != 0) {
    float* Cf = (float*)C32;
#pragma unroll
    for (int i = 0; i < 4; ++i) {
      const int mr = m0 + wr + i * 16 + quad * 4;
#pragma unroll
      for (int j = 0; j < 4; ++j) {
        const int ncl = wc + j * 16 + l15;
        const float bvv = bf2f(bias[n0 + ncl]);
#pragma unroll
        for (int r = 0; r < 4; ++r)
          Cf[(size_t)(mr + r) * Ntot + n0 + ncl] = acc[i][j][r] + bvv;
      }
    }
  } else {
    u16* Cb = (u16*)C16;
#pragma unroll
    for (int i = 0; i < 4; ++i) {
      const int mr = m0 + wr + i * 16 + quad * 4;
#pragma unroll
      for (int j = 0; j < 4; ++j) {
        const int ncl = wc + j * 16 + l15;
        const float bvv = bf2f(bias[n0 + ncl]);
#pragma unroll
        for (int r = 0; r < 4; ++r)
          Cb[(size_t)(mr + r) * Ntot + n0 + ncl] = f2bf(acc[i][j][r] + bvv);
      }
    }
  }
}

// ---------------------------------------------------------------------------
// Flash attention, S^T formulation (register-resident P). Q pre-scaled by
// QSCL at the projection, so exp2 applies directly to sacc.
//
// r5 post-mortem: neither gload_lds (r2-r4) nor restructured reg-staging (r5)
// reproduced r0's 74% L2 absorption; r5 added ~100MB mystery HBM writes.
// r6 = r0's PROVEN body (127us, verbatim staging+compute+store) with the two
// independently-validated geometry levers:
//  * 512 threads / 8 waves / 256 q-rows per block -> logical K/V traffic
//    halves (540->270MB) and staging cost per unit compute halves. Staging is
//    r0's exact code under `if (tid < 256)` (waves 0-3 stage as in r0; waves
//    4-7 wait at the barrier — staging is latency-bound, compute doubles).
//  * panel-colocating XCD swizzle (r3: fetch 467->308 under gload transport).
//  * s_setprio(1) around MFMA clusters (T5, attn-proven).
// ---------------------------------------------------------------------------
__global__ __launch_bounds__(512, 4)
void attn_s(const u16* __restrict__ QKV, u16* __restrict__ O)
{
  __shared__ __align__(16) u16 Klds[64 * 72];          // [kv][d], padded
  __shared__ __align__(16) unsigned int Vlds[64 * 32]; // V^T pairs, swizzled
  const int tid  = threadIdx.x;
  const int wave = tid >> 6, lane = tid & 63;
  const int quad = lane >> 4, l15 = lane & 15;

  // XCD-panel swizzle: all 8 qt of a panel -> same XCD, consecutive slots.
  const int i  = blockIdx.x;
  const int j  = i >> 3;
  const int qt = j & 7;
  const int g  = (i & 7) + ((j >> 3) << 3);      // panel id = h + 16*z
  const int h  = g & 15;
  const int z  = g >> 4;

  const u16* QKVb = QKV + (size_t)z * 2048 * 3072;
  u16* Ob = O + (size_t)z * 2048 * 1024;
  const int q0 = qt * 256;

  // Q fragments (B-operand of x32: n=l15 -> q, k=quad*8+jj -> d)
  short8 qf[2][2];
  const u16* Qb = QKVb + (size_t)(q0 + wave * 32) * 3072 + h * 64;
#pragma unroll
  for (int rt = 0; rt < 2; ++rt)
#pragma unroll
    for (int kh = 0; kh < 2; ++kh)
      qf[rt][kh] = *(const short8*)(Qb + (size_t)(rt * 16 + l15) * 3072 + kh * 32 + quad * 8);

  f32x4 oaccT[4][2] = {};    // [dt][rt]: C[m=d_local][n=q]
  float lrow[2] = {};

  // staging ids (r0 verbatim; valid for tid<256 => wave 0..3)
  const int ksrow = tid >> 2;        // 0..63
  const int kscb  = (tid & 3) * 16;  // 32B d-chunk
  const int vkvp = lane & 31;        // kv pair
  const int vd0  = wave * 16 + (lane >> 5) * 8;

  const u16* Kg = QKVb + 1024 + h * 64;
  const u16* Vg = QKVb + 2048 + h * 64;

  for (int kv0 = 0; kv0 < 2048; kv0 += 64) {
    __syncthreads();
    if (tid < 256) {
      const u16* kp = Kg + (size_t)(kv0 + ksrow) * 3072 + kscb;
      *(short8*)&Klds[ksrow * 72 + kscb]     = *(const short8*)kp;
      *(short8*)&Klds[ksrow * 72 + kscb + 8] = *(const short8*)(kp + 8);

      // V^T: phys u32 idx = d*32 + ((vkvp>>1 ^ (d&15))<<1) + (vkvp&1)
      const u16* v0p = Vg + (size_t)(kv0 + 2 * vkvp) * 3072 + vd0;
      short8 va  = *(const short8*)v0p;
      short8 vb2 = *(const short8*)(v0p + 3072);
      const int kb = vkvp >> 1, kl = vkvp & 1;
#pragma unroll
      for (int jj = 0; jj < 8; ++jj) {
        const int d = vd0 + jj;
        Vlds[d * 32 + ((kb ^ (d & 15)) << 1) + kl] =
            ((unsigned int)(unsigned short)va[jj]) |
            (((unsigned int)(unsigned short)vb2[jj]) << 16);
      }
    }
    __syncthreads();

    // S^T tiles: sacc[ct][rt], kv_local = ct*16 + quad*4 + r, q = rt*16 + l15
    f32x4 sacc[4][2] = {};
#pragma unroll
    for (int kh = 0; kh < 2; ++kh) {
      short8 kf[4];
#pragma unroll
      for (int ct = 0; ct < 4; ++ct)
        kf[ct] = *(const short8*)&Klds[(ct * 16 + l15) * 72 + kh * 32 + quad * 8];
      __builtin_amdgcn_s_setprio(1);
#pragma unroll
      for (int ct = 0; ct < 4; ++ct)
#pragma unroll
        for (int rt = 0; rt < 2; ++rt)
          sacc[ct][rt] = __builtin_amdgcn_mfma_f32_16x16x32_bf16(kf[ct], qf[rt][kh], sacc[ct][rt], 0, 0, 0);
      __builtin_amdgcn_s_setprio(0);
    }

    // softmax (max-free; Q pre-scaled) + pack P^T B-frags in registers
    sv4 p16[4][2];
#pragma unroll
    for (int rt = 0; rt < 2; ++rt) {
      float rs = 0.f;
#pragma unroll
      for (int ct = 0; ct < 4; ++ct) {
        float p0 = __builtin_amdgcn_exp2f(sacc[ct][rt][0]);
        float p1 = __builtin_amdgcn_exp2f(sacc[ct][rt][1]);
        float p2 = __builtin_amdgcn_exp2f(sacc[ct][rt][2]);
        float p3 = __builtin_amdgcn_exp2f(sacc[ct][rt][3]);
        rs += (p0 + p1) + (p2 + p3);
        u32x2 pw;
        pw[0] = pk_bf16(p0, p1);
        pw[1] = pk_bf16(p2, p3);
        p16[ct][rt] = __builtin_bit_cast(sv4, pw);
      }
      rs += __shfl_xor(rs, 16, 64);
      rs += __shfl_xor(rs, 32, 64);
      lrow[rt] += rs;
    }

    // PV: O^T += V^T * P^T, 16x16x16 per (dt, ct, rt)
    __builtin_amdgcn_s_setprio(1);
#pragma unroll
    for (int ct = 0; ct < 4; ++ct) {
#pragma unroll
      for (int dt = 0; dt < 4; ++dt) {
        const int d = dt * 16 + l15;
        const int idx = d * 32 + (((ct * 4 + quad) ^ (d & 15)) << 1);
        const sv4 vfr = *(const sv4*)&Vlds[idx];   // kv = ct*16+quad*4 .. +3
#pragma unroll
        for (int rt = 0; rt < 2; ++rt)
          oaccT[dt][rt] = mfma_16x16x16_bf16(vfr, p16[ct][rt], oaccT[dt][rt]);
      }
    }
    __builtin_amdgcn_s_setprio(0);
  }

  // store O[q][d]: q = q0+wave*32+rt*16+l15 (col), d = dt*16+quad*4+r (row)
#pragma unroll
  for (int rt = 0; rt < 2; ++rt) {
    const float inv = 1.f / lrow[rt];
    u16* Op = Ob + (size_t)(q0 + wave * 32 + rt * 16 + l15) * 1024 + h * 64;
#pragma unroll
    for (int dt = 0; dt < 4; ++dt) {
      u32x2 ow;
      ow[0] = pk_bf16(oaccT[dt][rt][0] * inv, oaccT[dt][rt][1] * inv);
      ow[1] = pk_bf16(oaccT[dt][rt][2] * inv, oaccT[dt][rt][3] * inv);
      *(sv4*)(Op + dt * 16 + quad * 4) = __builtin_bit_cast(sv4, ow);
    }
  }
}

// ---------------------------------------------------------------------------
extern "C" void kernel_launch(void* const* d_in, const int* in_sizes, int n_in,
                              void* d_out, int out_size, void* d_ws, size_t ws_size,
                              hipStream_t stream)
{
  // Common: flag + converted weights.
  int* flag = (int*)d_ws;
  u16* Wc   = (u16*)((char*)d_ws + 256);
  u16* bc   = Wc + (size_t)4 * 1048576;           // 4M u16
  char* after_wb = (char*)(bc + 4096);

  detect_dtype<<<1, 64, 0, stream>>>((const u16*)d_in[0], flag);
  convert_wb<<<2050, 256, 0, stream>>>(d_in[1], d_in[3], d_in[5], d_in[7],
                                       d_in[2], d_in[4], d_in[6], d_in[8],
                                       Wc, bc, flag);

  const size_t need_batched =
      (size_t)(after_wb - (char*)d_ws) + ((size_t)8192 * 3072 + (size_t)8192 * 1024) * 2;

  if (ws_size >= need_batched) {
    // ---- batched path: one launch per stage, full-device grids ----
    u16* QKV = (u16*)after_wb;
    u16* xO  = QKV + (size_t)8192 * 3072;   // xc before QKV-GEMM; O after attn

    convert_x_off<<<4096, 256, 0, stream>>>(d_in[0], xO, flag, 0);
    gemm_bt<<<dim3(64, 24), 256, 0, stream>>>(xO, Wc, Wc + 1048576, Wc + 2097152,
                                              bc, QKV, 3072, 1024);
    attn_s<<<512, 512, 0, stream>>>(QKV, xO);
    gemm_bt_out<<<dim3(64, 8), 256, 0, stream>>>(xO, Wc + (size_t)3 * 1048576,
                                                 bc + 3 * 1024, d_out, d_out,
                                                 1024, 1024, flag);
  } else {
    // ---- fallback: per-batch path (ws ~29.4 MB, proven) ----
    u16* xc   = (u16*)after_wb;
    u16* QKVb = xc + (size_t)2048 * 1024;
    u16* Obb  = QKVb + (size_t)2048 * 3072;
    for (int b = 0; b < 4; ++b) {
      convert_x_off<<<1024, 256, 0, stream>>>(d_in[0], xc, flag, b);
      gemm_bt<<<dim3(16, 24), 256, 0, stream>>>(xc, Wc, Wc + 1048576, Wc + 2097152,
                                                bc, QKVb, 3072, 1024);
      attn_s<<<128, 512, 0, stream>>>(QKVb, Obb);
      void* outb16 = (void*)((char*)d_out + (size_t)b * 2048 * 1024 * 2);
      void* outb32 = (void*)((char*)d_out + (size_t)b * 2048 * 1024 * 4);
      gemm_bt_out<<<dim3(16, 8), 256, 0, stream>>>(Obb, Wc + (size_t)3 * 1048576,
                                                   bc + 3 * 1024, outb16, outb32,
                                                   1024, 1024, flag);
    }
  }
}